// Round 10
// baseline (66.583 us; speedup 1.0000x reference)
//
#include <hip/hip_runtime.h>
#include <hip/hip_bf16.h>
#include <math.h>

#define NBATCH 8
#define NL 128
#define IND 512
#define DEPN 45
#define DEPD 16
#define WCOLS 528          // IN_DIM + DEP_DIM
#define NP 1664            // extended width (P1|P2|HT|D1|D2|pad)
#define C_P1 0
#define C_P2 512
#define C_HT 1024
#define C_D1 1536
#define C_D2 1581
#define C_PAD 1626

typedef __attribute__((ext_vector_type(8))) short bf16x8;
typedef __attribute__((ext_vector_type(4))) float f32x4;

__device__ inline ushort f2bf(float x) {
    __hip_bfloat16 b = __float2bfloat16(x);
    return *reinterpret_cast<ushort*>(&b);
}
__device__ inline float bf2f(ushort u) {
    __hip_bfloat16 b;
    *reinterpret_cast<ushort*>(&b) = u;
    return __bfloat162float(b);
}

// ================= k_prep (fully merged) =================
// blocks [0,64):    A_hi/A_lo = bf16-split of h*wpos (16 rows each);
//                   blk 0 also fills bias_ext P1/P2/HT + pad
// blocks [64,160):  B_hi/B_lo rows 0..1535 = split of W1h|W2h|Wg (16 rows each)
// blocks [160,162): zero B pad rows 1626..1663 (19 rows each)
// blocks [162,522): Z rows + D-bias: zi=(bid-162); t=zi%45, m=(zi/45)&1, dq=zi/90.
//                   Recomputes Y locally from emb (no cross-kernel dependency).
__global__ __launch_bounds__(256) void k_prep(
    const float* __restrict__ h, const unsigned char* __restrict__ mask,
    const float* __restrict__ emb,
    const float* __restrict__ W1, const float* __restrict__ W2,
    const float* __restrict__ Wg,
    const float* __restrict__ b1, const float* __restrict__ b2,
    const float* __restrict__ bg,
    ushort* __restrict__ A_hi, ushort* __restrict__ A_lo,
    ushort* __restrict__ B_hi, ushort* __restrict__ B_lo,
    float* __restrict__ bias_ext) {
    int bid = blockIdx.x;
    int tid = threadIdx.x;

    if (bid < 64) {
        // ---- A conversion: 16 rows, position-aware weight ----
        int rb = bid * 16;
        int b = rb >> 7;
        __shared__ int sflag, smin, smax;
        __shared__ float w16[16];
        if (tid == 0) { sflag = 0; smin = NL; smax = -1; }
        __syncthreads();
        const int* mi = (const int*)mask;
        if (tid < 128) {
            int v0 = mi[tid], v1 = mi[tid + 128];
            if ((unsigned)v0 > 1u || (unsigned)v1 > 1u) atomicOr(&sflag, 1);
        }
        __syncthreads();
        if (tid < 128) {
            int mval = sflag ? (int)mask[b * NL + tid] : mi[b * NL + tid];
            if (mval) { atomicMin(&smin, tid); atomicMax(&smax, tid); }
        }
        __syncthreads();
        if (tid < 16) {
            int any = (smax >= 0);
            int s = any ? smin : 0;
            int e = any ? smax : (NL - 1);
            int i = (rb & 127) + tid;
            const float invL = 1.0f / (float)NL;
            float w;
            if (i < s)      w = 1.0f - (float)(s - i) * invL;
            else if (i > e) w = 1.0f - (float)(i - e) * invL;
            else            w = 0.0f;
            int mval = sflag ? (int)mask[b * NL + i] : mi[b * NL + i];
            if (mval) w = 0.0f;
            w16[tid] = w;
        }
        __syncthreads();
        for (int idx = tid; idx < 16 * 128; idx += 256) {
            int r = idx >> 7, dc = (idx & 127) << 2;
            float4 hv = *(const float4*)&h[(size_t)(rb + r) * IND + dc];
            float wv = w16[r];
            hv.x *= wv; hv.y *= wv; hv.z *= wv; hv.w *= wv;
            ushort4 hi4;
            hi4.x = f2bf(hv.x); hi4.y = f2bf(hv.y); hi4.z = f2bf(hv.z); hi4.w = f2bf(hv.w);
            ushort4 lo4;
            lo4.x = f2bf(hv.x - bf2f(hi4.x));
            lo4.y = f2bf(hv.y - bf2f(hi4.y));
            lo4.z = f2bf(hv.z - bf2f(hi4.z));
            lo4.w = f2bf(hv.w - bf2f(hi4.w));
            *(ushort4*)&A_hi[(size_t)(rb + r) * IND + dc] = hi4;
            *(ushort4*)&A_lo[(size_t)(rb + r) * IND + dc] = lo4;
        }
        if (bid == 0) {
            for (int i = tid; i < 512; i += 256) {
                bias_ext[C_P1 + i] = b1[i];
                bias_ext[C_P2 + i] = b2[i];
                bias_ext[C_HT + i] = bg[i];
            }
            if (tid < NP - C_PAD) bias_ext[C_PAD + tid] = 0.f;
        }
    } else if (bid < 160) {
        // ---- B conversion rows 0..1535 ----
        int nb = (bid - 64) * 16;
        for (int idx = tid; idx < 16 * 128; idx += 256) {
            int r = idx >> 7, dc = (idx & 127) << 2;
            int n = nb + r;
            const float* src;
            if (n < 512)       src = W1 + (size_t)n * WCOLS + dc;
            else if (n < 1024) src = W2 + (size_t)(n - 512) * WCOLS + dc;
            else               src = Wg + (size_t)(n - 1024) * IND + dc;
            float4 wv = *(const float4*)src;
            ushort4 hi4;
            hi4.x = f2bf(wv.x); hi4.y = f2bf(wv.y); hi4.z = f2bf(wv.z); hi4.w = f2bf(wv.w);
            ushort4 lo4;
            lo4.x = f2bf(wv.x - bf2f(hi4.x));
            lo4.y = f2bf(wv.y - bf2f(hi4.y));
            lo4.z = f2bf(wv.z - bf2f(hi4.z));
            lo4.w = f2bf(wv.w - bf2f(hi4.w));
            *(ushort4*)&B_hi[(size_t)n * IND + dc] = hi4;
            *(ushort4*)&B_lo[(size_t)n * IND + dc] = lo4;
        }
    } else if (bid < 162) {
        // ---- zero B pad rows 1626..1663 ----
        int nb = 1626 + (bid - 160) * 19;
        ushort4 z4 = {0, 0, 0, 0};
        for (int idx = tid; idx < 19 * 128; idx += 256) {
            int r = idx >> 7, dc = (idx & 127) << 2;
            int n = nb + r;
            *(ushort4*)&B_hi[(size_t)n * IND + dc] = z4;
            *(ushort4*)&B_lo[(size_t)n * IND + dc] = z4;
        }
    } else {
        // ---- Z rows + D-bias ----
        int zi = bid - 162;
        int t = zi % 45;
        int m = (zi / 45) & 1;
        int dq = zi / 90;
        __shared__ float es[DEPD];
        __shared__ float ys[512];
        __shared__ float y1s[512];
        __shared__ float part[256];
        if (tid < DEPD) es[tid] = emb[t * DEPD + tid];
        __syncthreads();
        // ys = Y2[t] for m=0 (from W2 dep cols), Y1[t] for m=1 (from W1 dep cols)
        const float* Wdep = (m == 0) ? W2 : W1;
        for (int o = tid; o < 512; o += 256) {
            float s = 0.f;
#pragma unroll
            for (int e = 0; e < DEPD; e++) s += es[e] * Wdep[o * WCOLS + IND + e];
            ys[o] = s;
        }
        if (m == 0 && dq == 0) {
            for (int o = tid; o < 512; o += 256) {
                float s = 0.f;
#pragma unroll
                for (int e = 0; e < DEPD; e++) s += es[e] * W1[o * WCOLS + IND + e];
                y1s[o] = s;
            }
        }
        __syncthreads();
        // Z[d] = sum_o Wsrc[o][d] * ys[o]
        int dloc = tid & 127, half = tid >> 7;
        const float* Wsrc = (m == 0) ? W1 : W2;
        int d = dq * 128 + dloc;
        int obase = half * 256;
        float s = 0.f;
#pragma unroll 16
        for (int oo = 0; oo < 256; oo++)
            s += Wsrc[(size_t)(obase + oo) * WCOLS + d] * ys[obase + oo];
        part[tid] = s;
        __syncthreads();
        int row = ((m == 0) ? C_D1 : C_D2) + t;
        if (half == 0) {
            float tot = part[dloc] + part[128 + dloc];
            ushort hi = f2bf(tot);
            ushort lo = f2bf(tot - bf2f(hi));
            B_hi[(size_t)row * IND + d] = hi;
            B_lo[(size_t)row * IND + d] = lo;
        }
        if (dq == 0 && tid < 64) {
            const float* bb = (m == 0) ? b1 : b2;
            float sb = 0.f;
#pragma unroll
            for (int k = 0; k < 8; k++) sb += bb[tid + k * 64] * ys[tid + k * 64];
            if (m == 0) {
#pragma unroll
                for (int k = 0; k < 8; k++) sb += y1s[tid + k * 64] * ys[tid + k * 64];
            }
            for (int off = 32; off; off >>= 1) sb += __shfl_down(sb, off, 64);
            if (tid == 0) bias_ext[row] = sb;
        }
    }
}

// ================= k3: Pout = A @ B^T + bias_ext  (MFMA, hi/lo bf16) =================
// 128 thr = 2 waves; wave tile 32x32; block tile 64m x 32n; grid (16, 52).
// HT col-blocks (y in [32,48)) write transposed bf16 hi/lo HTt[b][o][j]
// instead of fp32 Pout (k5's MFMA B-operand layout).
#define LOADSET(P, KS) \
    P##a0h = *(const bf16x8*)(A_hi + (size_t)rA0 * IND + (KS) * 32 + kg8); \
    P##a0l = *(const bf16x8*)(A_lo + (size_t)rA0 * IND + (KS) * 32 + kg8); \
    P##a1h = *(const bf16x8*)(A_hi + (size_t)rA1 * IND + (KS) * 32 + kg8); \
    P##a1l = *(const bf16x8*)(A_lo + (size_t)rA1 * IND + (KS) * 32 + kg8); \
    P##b0h = *(const bf16x8*)(B_hi + (size_t)cB0 * IND + (KS) * 32 + kg8); \
    P##b0l = *(const bf16x8*)(B_lo + (size_t)cB0 * IND + (KS) * 32 + kg8); \
    P##b1h = *(const bf16x8*)(B_hi + (size_t)cB1 * IND + (KS) * 32 + kg8); \
    P##b1l = *(const bf16x8*)(B_lo + (size_t)cB1 * IND + (KS) * 32 + kg8);

#define MFMASET(P) \
    acc00 = __builtin_amdgcn_mfma_f32_16x16x32_bf16(P##a0h, P##b0h, acc00, 0, 0, 0); \
    acc00 = __builtin_amdgcn_mfma_f32_16x16x32_bf16(P##a0h, P##b0l, acc00, 0, 0, 0); \
    acc00 = __builtin_amdgcn_mfma_f32_16x16x32_bf16(P##a0l, P##b0h, acc00, 0, 0, 0); \
    acc01 = __builtin_amdgcn_mfma_f32_16x16x32_bf16(P##a0h, P##b1h, acc01, 0, 0, 0); \
    acc01 = __builtin_amdgcn_mfma_f32_16x16x32_bf16(P##a0h, P##b1l, acc01, 0, 0, 0); \
    acc01 = __builtin_amdgcn_mfma_f32_16x16x32_bf16(P##a0l, P##b1h, acc01, 0, 0, 0); \
    acc10 = __builtin_amdgcn_mfma_f32_16x16x32_bf16(P##a1h, P##b0h, acc10, 0, 0, 0); \
    acc10 = __builtin_amdgcn_mfma_f32_16x16x32_bf16(P##a1h, P##b0l, acc10, 0, 0, 0); \
    acc10 = __builtin_amdgcn_mfma_f32_16x16x32_bf16(P##a1l, P##b0h, acc10, 0, 0, 0); \
    acc11 = __builtin_amdgcn_mfma_f32_16x16x32_bf16(P##a1h, P##b1h, acc11, 0, 0, 0); \
    acc11 = __builtin_amdgcn_mfma_f32_16x16x32_bf16(P##a1h, P##b1l, acc11, 0, 0, 0); \
    acc11 = __builtin_amdgcn_mfma_f32_16x16x32_bf16(P##a1l, P##b1h, acc11, 0, 0, 0);

__global__ __launch_bounds__(128) void k3_gemm(
    const ushort* __restrict__ A_hi, const ushort* __restrict__ A_lo,
    const ushort* __restrict__ B_hi, const ushort* __restrict__ B_lo,
    const float* __restrict__ bias_ext, float* __restrict__ Pout,
    ushort* __restrict__ HTt_hi, ushort* __restrict__ HTt_lo) {
    int tid = threadIdx.x;
    int wid = tid >> 6, lane = tid & 63;
    int lrow = lane & 15, kg8 = (lane >> 4) << 3;
    int mbase = blockIdx.x * 64 + wid * 32;
    int nbase = blockIdx.y * 32;
    int rA0 = mbase + lrow, rA1 = rA0 + 16;
    int cB0 = nbase + lrow, cB1 = cB0 + 16;

    f32x4 acc00 = {0.f, 0.f, 0.f, 0.f};
    f32x4 acc01 = acc00, acc10 = acc00, acc11 = acc00;
    bf16x8 pa0h, pa0l, pa1h, pa1l, pb0h, pb0l, pb1h, pb1l;
    bf16x8 qa0h, qa0l, qa1h, qa1l, qb0h, qb0l, qb1h, qb1l;

    LOADSET(p, 0)
#pragma unroll
    for (int ks = 0; ks < 16; ks += 2) {
        LOADSET(q, ks + 1)
        MFMASET(p)
        int kn = (ks + 2) & 15;      // last iter: dummy reload of 0 (unused)
        LOADSET(p, kn)
        MFMASET(q)
    }

    int r0 = (lane >> 4) << 2;
    int col0 = nbase + lrow;
    int col1 = col0 + 16;
    float bv0 = bias_ext[col0];
    float bv1 = bias_ext[col1];

    if (nbase >= C_HT && nbase < C_HT + 512) {
        // HT block: write transposed bf16 hi/lo HTt[b][o][j]
        int b = mbase >> 7;
        int o0 = col0 - C_HT, o1 = col1 - C_HT;
        int j0 = (mbase & 127) + r0;
        ushort4 h4, l4;
        float v0f, v1f, v2f, v3f;
#define PACK_STORE(ACC, BV, OO, JJ) \
        v0f = ACC[0] + BV; v1f = ACC[1] + BV; v2f = ACC[2] + BV; v3f = ACC[3] + BV; \
        h4.x = f2bf(v0f); h4.y = f2bf(v1f); h4.z = f2bf(v2f); h4.w = f2bf(v3f); \
        l4.x = f2bf(v0f - bf2f(h4.x)); l4.y = f2bf(v1f - bf2f(h4.y)); \
        l4.z = f2bf(v2f - bf2f(h4.z)); l4.w = f2bf(v3f - bf2f(h4.w)); \
        *(ushort4*)&HTt_hi[((size_t)(b * 512 + (OO))) * 128 + (JJ)] = h4; \
        *(ushort4*)&HTt_lo[((size_t)(b * 512 + (OO))) * 128 + (JJ)] = l4;
        PACK_STORE(acc00, bv0, o0, j0)
        PACK_STORE(acc01, bv1, o1, j0)
        PACK_STORE(acc10, bv0, o0, j0 + 16)
        PACK_STORE(acc11, bv1, o1, j0 + 16)
#undef PACK_STORE
    } else {
#pragma unroll
        for (int r = 0; r < 4; ++r) {
            int row0 = mbase + r0 + r;
            int row1 = row0 + 16;
            Pout[(size_t)row0 * NP + col0] = acc00[r] + bv0;
            Pout[(size_t)row0 * NP + col1] = acc01[r] + bv1;
            Pout[(size_t)row1 * NP + col0] = acc10[r] + bv0;
            Pout[(size_t)row1 * NP + col1] = acc11[r] + bv1;
        }
    }
}

// ================= k5: scores + stable softmax + S@HT (MFMA) + relu =================
// grid 32 = 8 batches x 4 rowgroups of 32 rows.  c0 = P1.P2 cancels in the
// softmax except through the +1e-6: inv = 1/(sum_a + 1e-6*exp(-(c0+M))).
__global__ __launch_bounds__(256) void k5_out(
    const float* __restrict__ P, const int* __restrict__ dep,
    const ushort* __restrict__ HTt_hi, const ushort* __restrict__ HTt_lo,
    const float* __restrict__ bias, float* __restrict__ out) {
    int blk = blockIdx.x;
    int b = blk >> 2, rg = blk & 3;
    int i0 = b * 128 + rg * 32;
    int tid = threadIdx.x;
    __shared__ float c0s[32];
    __shared__ float combs[32][48];
    __shared__ ushort Sh[32][128];
    __shared__ ushort Sl[32][128];
    __shared__ float invs[32];

    // phase A: c0[row] = P1[row] . P2[row]   (8 threads per row)
    {
        int row = tid >> 3, ch = (tid & 7) * 64;
        const float* p1 = P + (size_t)(i0 + row) * NP + C_P1 + ch;
        const float* p2 = P + (size_t)(i0 + row) * NP + C_P2 + ch;
        float s = 0.f;
#pragma unroll
        for (int k = 0; k < 16; k++) {
            float4 a = *(const float4*)(p1 + k * 4);
            float4 c = *(const float4*)(p2 + k * 4);
            s += a.x * c.x + a.y * c.y + a.z * c.z + a.w * c.w;
        }
        s += __shfl_xor(s, 1, 64); s += __shfl_xor(s, 2, 64); s += __shfl_xor(s, 4, 64);
        if ((tid & 7) == 0) c0s[row] = s;
    }
    // phase B: combs[row][t] = D1 + D2
    for (int idx = tid; idx < 32 * 45; idx += 256) {
        int r = idx / 45, t = idx - r * 45;
        const float* Prow = P + (size_t)(i0 + r) * NP;
        combs[r][t] = Prow[C_D1 + t] + Prow[C_D2 + t];
    }
    __syncthreads();

    // phase C: stable scores, S bf16 hi/lo, inv[row]
    {
        int row = tid >> 3, j0 = (tid & 7) * 16;
        const int* dp = dep + (size_t)(i0 + row) * NL + j0;
        float vals[16]; int valid[16];
        float M = -3.0e38f;
#pragma unroll
        for (int jj = 0; jj < 16; jj++) {
            int tt = dp[jj];
            valid[jj] = (tt != 0);
            float v = combs[row][tt];
            vals[jj] = v;
            if (valid[jj]) M = fmaxf(M, v);
        }
        M = fmaxf(M, __shfl_xor(M, 1, 64));
        M = fmaxf(M, __shfl_xor(M, 2, 64));
        M = fmaxf(M, __shfl_xor(M, 4, 64));
        float sum = 0.f;
#pragma unroll
        for (int jj = 0; jj < 16; jj++) {
            float a = valid[jj] ? expf(vals[jj] - M) : 0.f;
            sum += a;
            ushort hi = f2bf(a);
            Sh[row][j0 + jj] = hi;
            Sl[row][j0 + jj] = f2bf(a - bf2f(hi));
        }
        sum += __shfl_xor(sum, 1, 64);
        sum += __shfl_xor(sum, 2, 64);
        sum += __shfl_xor(sum, 4, 64);
        if ((tid & 7) == 0) {
            float corr = 1e-6f * expf(-(c0s[row] + M));   // M=-inf -> inf -> inv=0
            invs[row] = 1.0f / (sum + corr);
        }
    }
    __syncthreads();

    // phase D: out[32 x 512] = S(32x128) @ HTt_b^T via MFMA (3-term hi/lo)
    int wid = tid >> 6, lane = tid & 63;
    int lrow = lane & 15, kg8 = (lane >> 4) << 3;
    int obase = wid * 128;
    f32x4 z = {0.f, 0.f, 0.f, 0.f};
    f32x4 acc0[8] = {z, z, z, z, z, z, z, z};
    f32x4 acc1[8] = {z, z, z, z, z, z, z, z};
#pragma unroll
    for (int ks = 0; ks < 4; ks++) {
        bf16x8 a0h = *(const bf16x8*)&Sh[lrow][ks * 32 + kg8];
        bf16x8 a0l = *(const bf16x8*)&Sl[lrow][ks * 32 + kg8];
        bf16x8 a1h = *(const bf16x8*)&Sh[16 + lrow][ks * 32 + kg8];
        bf16x8 a1l = *(const bf16x8*)&Sl[16 + lrow][ks * 32 + kg8];
#pragma unroll
        for (int nf = 0; nf < 8; nf++) {
            int o = obase + nf * 16 + lrow;
            size_t base = ((size_t)(b * 512 + o)) * 128 + ks * 32 + kg8;
            bf16x8 bh = *(const bf16x8*)(HTt_hi + base);
            bf16x8 bl = *(const bf16x8*)(HTt_lo + base);
            acc0[nf] = __builtin_amdgcn_mfma_f32_16x16x32_bf16(a0h, bh, acc0[nf], 0, 0, 0);
            acc0[nf] = __builtin_amdgcn_mfma_f32_16x16x32_bf16(a0h, bl, acc0[nf], 0, 0, 0);
            acc0[nf] = __builtin_amdgcn_mfma_f32_16x16x32_bf16(a0l, bh, acc0[nf], 0, 0, 0);
            acc1[nf] = __builtin_amdgcn_mfma_f32_16x16x32_bf16(a1h, bh, acc1[nf], 0, 0, 0);
            acc1[nf] = __builtin_amdgcn_mfma_f32_16x16x32_bf16(a1h, bl, acc1[nf], 0, 0, 0);
            acc1[nf] = __builtin_amdgcn_mfma_f32_16x16x32_bf16(a1l, bh, acc1[nf], 0, 0, 0);
        }
    }

    int r0 = (lane >> 4) << 2;
#pragma unroll
    for (int nf = 0; nf < 8; nf++) {
        int o = obase + nf * 16 + lrow;
        float bv = bias[o];
#pragma unroll
        for (int r = 0; r < 4; r++) {
            int i0r = r0 + r;
            float v0 = acc0[nf][r] * invs[i0r] + bv;
            float v1 = acc1[nf][r] * invs[16 + i0r] + bv;
            out[(size_t)(i0 + i0r) * 512 + o] = fmaxf(v0, 0.f);
            out[(size_t)(i0 + 16 + i0r) * 512 + o] = fmaxf(v1, 0.f);
        }
    }
}

extern "C" void kernel_launch(void* const* d_in, const int* in_sizes, int n_in,
                              void* d_out, int out_size, void* d_ws, size_t ws_size,
                              hipStream_t stream) {
    const float* h    = (const float*)d_in[0];
    const int* dep    = (const int*)d_in[1];
    const unsigned char* mask = (const unsigned char*)d_in[2];
    const float* emb  = (const float*)d_in[3];
    const float* W1   = (const float*)d_in[4];
    const float* b1   = (const float*)d_in[5];
    const float* W2   = (const float*)d_in[6];
    const float* b2   = (const float*)d_in[7];
    const float* Wg   = (const float*)d_in[8];
    const float* bg   = (const float*)d_in[9];
    const float* bias = (const float*)d_in[10];
    float* out = (float*)d_out;

    char* p = (char*)d_ws;
    ushort* A_hi = (ushort*)p;  p += (size_t)1024 * 512 * 2;   // 1 MB
    ushort* A_lo = (ushort*)p;  p += (size_t)1024 * 512 * 2;
    ushort* B_hi = (ushort*)p;  p += (size_t)1664 * 512 * 2;   // 1.7 MB
    ushort* B_lo = (ushort*)p;  p += (size_t)1664 * 512 * 2;
    ushort* HTt_hi = (ushort*)p; p += (size_t)8 * 512 * 128 * 2;  // 1 MB
    ushort* HTt_lo = (ushort*)p; p += (size_t)8 * 512 * 128 * 2;
    float* bias_ext = (float*)p; p += 1664 * 4;
    float* Pout = (float*)p;    // 1024*1664*4 = 6.8 MB

    k_prep<<<522, 256, 0, stream>>>(h, mask, emb, W1, W2, Wg, b1, b2, bg,
                                    A_hi, A_lo, B_hi, B_lo, bias_ext);
    dim3 g3(16, 52);
    k3_gemm<<<g3, 128, 0, stream>>>(A_hi, A_lo, B_hi, B_lo, bias_ext, Pout,
                                    HTt_hi, HTt_lo);
    k5_out<<<32, 256, 0, stream>>>(Pout, dep, HTt_hi, HTt_lo, bias, out);
}